// Round 1
// baseline (1001.891 us; speedup 1.0000x reference)
//
#include <hip/hip_runtime.h>
#include <cstdint>
#include <cstddef>

#define IN_DIM  256
#define H_DIM   256
#define OUT_DIM 128
#define MEDGES  20000

// ======================= CSR build =======================

__global__ void hist_kernel(const int* __restrict__ e_idx, const int* __restrict__ v_idx,
                            int* __restrict__ cnt_e, int* __restrict__ cnt_v, int nnz)
{
    int i = blockIdx.x * blockDim.x + threadIdx.x;
    if (i < nnz) {
        atomicAdd(&cnt_e[e_idx[i]], 1);
        atomicAdd(&cnt_v[v_idx[i]], 1);
    }
}

#define SCAN_B 1024
__global__ void scan_block_kernel(const int* __restrict__ in, int* __restrict__ out,
                                  int* __restrict__ bsums, int n)
{
    __shared__ int s[SCAN_B];
    int gid = blockIdx.x * SCAN_B + threadIdx.x;
    int x = (gid < n) ? in[gid] : 0;
    s[threadIdx.x] = x;
    __syncthreads();
    for (int off = 1; off < SCAN_B; off <<= 1) {
        int v = (threadIdx.x >= off) ? s[threadIdx.x - off] : 0;
        __syncthreads();
        s[threadIdx.x] += v;
        __syncthreads();
    }
    if (gid < n) out[gid] = s[threadIdx.x] - x;   // exclusive
    if (threadIdx.x == SCAN_B - 1) bsums[blockIdx.x] = s[SCAN_B - 1];
}

__global__ void scan_top_kernel(int* bsums, int nb)
{
    if (threadIdx.x == 0 && blockIdx.x == 0) {
        int run = 0;
        for (int i = 0; i < nb; ++i) { int v = bsums[i]; bsums[i] = run; run += v; }
    }
}

__global__ void scan_add_kernel(int* __restrict__ out, const int* __restrict__ bsums, int n)
{
    int gid = blockIdx.x * SCAN_B + threadIdx.x;
    if (gid < n) out[gid] += bsums[blockIdx.x];
}

__global__ void set_tail_kernel(int* e_off, int* v_off, int nnz, int m, int n)
{
    if (threadIdx.x == 0 && blockIdx.x == 0) { e_off[m] = nnz; v_off[n] = nnz; }
}

__global__ void scatter_kernel(const int* __restrict__ e_idx, const int* __restrict__ v_idx,
                               const int* __restrict__ e_off, const int* __restrict__ v_off,
                               int* __restrict__ cur_e, int* __restrict__ cur_v,
                               int* __restrict__ e_list, int* __restrict__ v_list, int nnz)
{
    int i = blockIdx.x * blockDim.x + threadIdx.x;
    if (i < nnz) {
        int e = e_idx[i], v = v_idx[i];
        int pe = e_off[e] + atomicAdd(&cur_e[e], 1);
        e_list[pe] = v;
        int pv = v_off[v] + atomicAdd(&cur_v[v], 1);
        v_list[pv] = e;
    }
}

// ======================= segment mean (gather form) =======================
// One block per segment t; blockDim.x == D (feature dim). Coalesced row reads.
__global__ void seg_mean_gather(const float* __restrict__ src, float* __restrict__ dst,
                                const int* __restrict__ off, const int* __restrict__ lst,
                                int do_relu)
{
    int t   = blockIdx.x;
    int col = threadIdx.x;
    int D   = blockDim.x;
    int beg = off[t], end = off[t + 1];
    float acc = 0.f;
    int j = beg;
    for (; j + 1 < end; j += 2) {                 // unroll-2 for load ILP
        int i0 = lst[j], i1 = lst[j + 1];
        float a = src[(size_t)i0 * D + col];
        float b = src[(size_t)i1 * D + col];
        acc += a;
        acc += b;
    }
    if (j < end) acc += src[(size_t)lst[j] * D + col];
    int cnt = end - beg;
    float r = (cnt > 0) ? acc / (float)cnt : 0.f;
    if (do_relu) r = fmaxf(r, 0.f);
    dst[(size_t)t * D + col] = r;
}

// ======================= fp32 tiled GEMM + bias =======================
// C[R x Cc] = A[R x K] @ W[K x Cc] + bias.  64x64 tile, BK=16, 256 thr, 4x4/thread.
#define BM 64
#define BN 64
#define BK 16
__global__ __launch_bounds__(256) void gemm_bias(const float* __restrict__ A,
                                                 const float* __restrict__ W,
                                                 const float* __restrict__ bias,
                                                 float* __restrict__ C,
                                                 int R, int K, int Cc)
{
    __shared__ __align__(16) float As[BK][68];   // A^T tile: As[k][row]
    __shared__ __align__(16) float Bs[BK][72];   // Bs[k][col]

    int tid  = threadIdx.x;
    int row0 = blockIdx.y * BM;
    int col0 = blockIdx.x * BN;

    int tr = tid >> 4;        // 0..15
    int tc = tid & 15;        // 0..15

    float acc[4][4] = {};

    int ar = tid >> 2;        // 0..63  (A row within tile)
    int ac = tid & 3;         // 0..3   (float4 index within 16-wide K slice)
    int kr = tid >> 4;        // 0..15  (W k-row)
    int cc = tid & 15;        // 0..15  (W float4 col index)

    for (int k0 = 0; k0 < K; k0 += BK) {
        // stage A (transposed into LDS)
        float4 av4 = make_float4(0.f, 0.f, 0.f, 0.f);
        int grow = row0 + ar;
        if (grow < R) av4 = *(const float4*)&A[(size_t)grow * K + k0 + 4 * ac];
        As[4 * ac + 0][ar] = av4.x;
        As[4 * ac + 1][ar] = av4.y;
        As[4 * ac + 2][ar] = av4.z;
        As[4 * ac + 3][ar] = av4.w;
        // stage W
        *(float4*)&Bs[kr][4 * cc] =
            *(const float4*)&W[(size_t)(k0 + kr) * Cc + col0 + 4 * cc];
        __syncthreads();

#pragma unroll
        for (int kk = 0; kk < BK; ++kk) {
            float4 a = *(const float4*)&As[kk][4 * tr];
            float4 b = *(const float4*)&Bs[kk][4 * tc];
            acc[0][0] += a.x * b.x; acc[0][1] += a.x * b.y; acc[0][2] += a.x * b.z; acc[0][3] += a.x * b.w;
            acc[1][0] += a.y * b.x; acc[1][1] += a.y * b.y; acc[1][2] += a.y * b.z; acc[1][3] += a.y * b.w;
            acc[2][0] += a.z * b.x; acc[2][1] += a.z * b.y; acc[2][2] += a.z * b.z; acc[2][3] += a.z * b.w;
            acc[3][0] += a.w * b.x; acc[3][1] += a.w * b.y; acc[3][2] += a.w * b.z; acc[3][3] += a.w * b.w;
        }
        __syncthreads();
    }

    int colb = col0 + 4 * tc;
    float4 bv = *(const float4*)&bias[colb];
#pragma unroll
    for (int i = 0; i < 4; ++i) {
        int grow = row0 + 4 * tr + i;
        if (grow < R) {
            float4 o;
            o.x = acc[i][0] + bv.x;
            o.y = acc[i][1] + bv.y;
            o.z = acc[i][2] + bv.z;
            o.w = acc[i][3] + bv.w;
            *(float4*)&C[(size_t)grow * Cc + colb] = o;
        }
    }
}

// ======================= link head =======================
// One wave (64 lanes) per link: mean of K=2 member rows, dot fc_w, sigmoid.
__global__ void link_head(const float* __restrict__ h2, const int* __restrict__ link,
                          const float* __restrict__ fc_w, const float* __restrict__ fc_b,
                          float* __restrict__ out, int L)
{
    int gtid = blockIdx.x * blockDim.x + threadIdx.x;
    int wid  = gtid >> 6;
    int lane = threadIdx.x & 63;
    if (wid >= L) return;
    int a = link[2 * wid + 0];
    int b = link[2 * wid + 1];
    float acc = 0.f;
#pragma unroll
    for (int j = lane; j < OUT_DIM; j += 64) {
        float m = 0.5f * (h2[(size_t)a * OUT_DIM + j] + h2[(size_t)b * OUT_DIM + j]);
        acc += m * fc_w[j];
    }
#pragma unroll
    for (int off = 32; off; off >>= 1) acc += __shfl_xor(acc, off, 64);
    if (lane == 0) out[wid] = 1.f / (1.f + expf(-(acc + fc_b[0])));
}

// ======================= launch =======================

static inline size_t align_up(size_t x, size_t a) { return (x + a - 1) & ~(a - 1); }

extern "C" void kernel_launch(void* const* d_in, const int* in_sizes, int n_in,
                              void* d_out, int out_size, void* d_ws, size_t ws_size,
                              hipStream_t stream)
{
    const float* X   = (const float*)d_in[0];
    const float* W1  = (const float*)d_in[1];
    const float* b1  = (const float*)d_in[2];
    const float* W2  = (const float*)d_in[3];
    const float* b2  = (const float*)d_in[4];
    const float* fcw = (const float*)d_in[5];
    const float* fcb = (const float*)d_in[6];
    const int* v_idx = (const int*)d_in[7];
    const int* e_idx = (const int*)d_in[8];
    const int* link  = (const int*)d_in[9];
    float* out = (float*)d_out;

    const int NNZ = in_sizes[7];
    const int N   = in_sizes[0] / IN_DIM;
    const int L   = in_sizes[9] / 2;
    const int M   = MEDGES;

    char* p = (char*)d_ws;
    auto carve = [&](size_t bytes) -> void* {
        void* r = (void*)p;
        p += align_up(bytes, 256);
        return r;
    };
    float* h1    = (float*)carve((size_t)N * H_DIM * 4);   // reused as h2 (N x 128)
    float* Xe    = (float*)carve((size_t)M * H_DIM * 4);   // reused as He
    float* Y1    = (float*)carve((size_t)M * H_DIM * 4);   // reused as Y2
    int*   e_off = (int*)carve((size_t)(M + 1) * 4);
    int*   v_off = (int*)carve((size_t)(N + 1) * 4);
    int*   cnt_e = (int*)carve((size_t)M * 4);
    int*   cnt_v = (int*)carve((size_t)N * 4);
    int*   cur_e = (int*)carve((size_t)M * 4);
    int*   cur_v = (int*)carve((size_t)N * 4);
    int*   e_lst = (int*)carve((size_t)NNZ * 4);
    int*   v_lst = (int*)carve((size_t)NNZ * 4);
    int*   bsums = (int*)carve(4096);

    hipMemsetAsync(cnt_e, 0, (size_t)M * 4, stream);
    hipMemsetAsync(cnt_v, 0, (size_t)N * 4, stream);
    hipMemsetAsync(cur_e, 0, (size_t)M * 4, stream);
    hipMemsetAsync(cur_v, 0, (size_t)N * 4, stream);

    const int tb = 256;
    hist_kernel<<<(NNZ + tb - 1) / tb, tb, 0, stream>>>(e_idx, v_idx, cnt_e, cnt_v, NNZ);

    int nbE = (M + SCAN_B - 1) / SCAN_B;
    scan_block_kernel<<<nbE, SCAN_B, 0, stream>>>(cnt_e, e_off, bsums, M);
    scan_top_kernel<<<1, 64, 0, stream>>>(bsums, nbE);
    scan_add_kernel<<<nbE, SCAN_B, 0, stream>>>(e_off, bsums, M);

    int nbV = (N + SCAN_B - 1) / SCAN_B;
    scan_block_kernel<<<nbV, SCAN_B, 0, stream>>>(cnt_v, v_off, bsums, N);
    scan_top_kernel<<<1, 64, 0, stream>>>(bsums, nbV);
    scan_add_kernel<<<nbV, SCAN_B, 0, stream>>>(v_off, bsums, N);

    set_tail_kernel<<<1, 64, 0, stream>>>(e_off, v_off, NNZ, M, N);

    scatter_kernel<<<(NNZ + tb - 1) / tb, tb, 0, stream>>>(e_idx, v_idx, e_off, v_off,
                                                           cur_e, cur_v, e_lst, v_lst, NNZ);

    // ---- conv1 (GEMM commuted to edge level) ----
    // Xe = mean_v2e(X)           [M x 256]
    seg_mean_gather<<<M, IN_DIM, 0, stream>>>(X, Xe, e_off, e_lst, 0);
    // Y1 = Xe @ W1 + b1          [M x 256]
    gemm_bias<<<dim3(H_DIM / BN, (M + BM - 1) / BM), 256, 0, stream>>>(Xe, W1, b1, Y1, M, IN_DIM, H_DIM);
    // h1 = relu(mean_e2v(Y1))    [N x 256]
    seg_mean_gather<<<N, H_DIM, 0, stream>>>(Y1, h1, v_off, v_lst, 1);

    // ---- conv2 ----
    // He = mean_v2e(h1)          [M x 256]  (reuses Xe)
    seg_mean_gather<<<M, H_DIM, 0, stream>>>(h1, Xe, e_off, e_lst, 0);
    // Y2 = He @ W2 + b2          [M x 128]  (reuses Y1)
    gemm_bias<<<dim3(OUT_DIM / BN, (M + BM - 1) / BM), 256, 0, stream>>>(Xe, W2, b2, Y1, M, H_DIM, OUT_DIM);
    // h2 = relu(mean_e2v(Y2))    [N x 128]  (reuses h1 buffer)
    seg_mean_gather<<<N, OUT_DIM, 0, stream>>>(Y1, h1, v_off, v_lst, 1);

    // ---- link head ----
    link_head<<<((size_t)L * 64 + 255) / 256, 256, 0, stream>>>(h1, link, fcw, fcb, out, L);
}

// Round 3
// 677.502 us; speedup vs baseline: 1.4788x; 1.4788x over previous
//
#include <hip/hip_runtime.h>
#include <cstdint>
#include <cstddef>

#define IN_DIM  256
#define H_DIM   256
#define OUT_DIM 128
#define MEDGES  20000

typedef unsigned short u16;
typedef unsigned int   u32;

__device__ __forceinline__ float bf2f(u16 u) {
    u32 x = ((u32)u) << 16;
    float f;
    __builtin_memcpy(&f, &x, 4);
    return f;
}
// round-to-nearest-even float -> bf16 (finite inputs)
__device__ __forceinline__ u16 f2bf(float f) {
    u32 x;
    __builtin_memcpy(&x, &f, 4);
    u32 r = x + 0x7fffu + ((x >> 16) & 1u);
    return (u16)(r >> 16);
}

// ======================= convert X fp32 -> bf16 =======================
__global__ void cvt_f32_bf16(const float4* __restrict__ src, ushort4* __restrict__ dst, int n4)
{
    int i = blockIdx.x * blockDim.x + threadIdx.x;
    if (i < n4) {
        float4 v = src[i];
        ushort4 o;
        o.x = f2bf(v.x); o.y = f2bf(v.y); o.z = f2bf(v.z); o.w = f2bf(v.w);
        dst[i] = o;
    }
}

// ======================= CSR build =======================

__global__ void hist_rank_kernel(const int* __restrict__ e_idx, const int* __restrict__ v_idx,
                                 int* __restrict__ cnt_e, int* __restrict__ cnt_v,
                                 int* __restrict__ rank_e, int* __restrict__ rank_v, int nnz)
{
    int i = blockIdx.x * blockDim.x + threadIdx.x;
    if (i < nnz) {
        rank_e[i] = atomicAdd(&cnt_e[e_idx[i]], 1);
        rank_v[i] = atomicAdd(&cnt_v[v_idx[i]], 1);
    }
}

#define SCAN_B 1024
__global__ void scan_block_kernel(const int* __restrict__ in, int* __restrict__ out,
                                  int* __restrict__ bsums, int n)
{
    __shared__ int s[SCAN_B];
    int gid = blockIdx.x * SCAN_B + threadIdx.x;
    int x = (gid < n) ? in[gid] : 0;
    s[threadIdx.x] = x;
    __syncthreads();
    for (int off = 1; off < SCAN_B; off <<= 1) {
        int v = (threadIdx.x >= off) ? s[threadIdx.x - off] : 0;
        __syncthreads();
        s[threadIdx.x] += v;
        __syncthreads();
    }
    if (gid < n) out[gid] = s[threadIdx.x] - x;   // exclusive
    if (threadIdx.x == SCAN_B - 1) bsums[blockIdx.x] = s[SCAN_B - 1];
}

__global__ void scan_top_kernel(int* bsums, int nb)
{
    if (threadIdx.x == 0 && blockIdx.x == 0) {
        int run = 0;
        for (int i = 0; i < nb; ++i) { int v = bsums[i]; bsums[i] = run; run += v; }
    }
}

__global__ void scan_add_kernel(int* __restrict__ out, const int* __restrict__ bsums, int n)
{
    int gid = blockIdx.x * SCAN_B + threadIdx.x;
    if (gid < n) out[gid] += bsums[blockIdx.x];
}

__global__ void set_tail_kernel(int* e_off, int* v_off, int nnz, int m, int n)
{
    if (threadIdx.x == 0 && blockIdx.x == 0) { e_off[m] = nnz; v_off[n] = nnz; }
}

__global__ void scatter_kernel(const int* __restrict__ e_idx, const int* __restrict__ v_idx,
                               const int* __restrict__ e_off, const int* __restrict__ v_off,
                               const int* __restrict__ rank_e, const int* __restrict__ rank_v,
                               int* __restrict__ e_list, int* __restrict__ v_list, int nnz)
{
    int i = blockIdx.x * blockDim.x + threadIdx.x;
    if (i < nnz) {
        int e = e_idx[i], v = v_idx[i];
        e_list[e_off[e] + rank_e[i]] = v;
        v_list[v_off[v] + rank_v[i]] = e;
    }
}

// ======================= segment mean (gather, bf16 src) =======================
// One block per segment; blockDim.x = D/2; each thread owns one bf16x2 column pair.

// bf16 src -> fp32 dst (v2e aggregation feeding the GEMM)
__global__ void seg_mean_b2f(const ushort2* __restrict__ src, float* __restrict__ dst,
                             const int* __restrict__ off, const int* __restrict__ lst)
{
    int t  = blockIdx.x;
    int c  = threadIdx.x;          // column pair
    int Dh = blockDim.x;           // D/2
    int beg = off[t], end = off[t + 1];
    float ax = 0.f, ay = 0.f;
    int j = beg;
    for (; j + 1 < end; j += 2) {
        int i0 = lst[j], i1 = lst[j + 1];
        ushort2 a = src[(size_t)i0 * Dh + c];
        ushort2 b = src[(size_t)i1 * Dh + c];
        ax += bf2f(a.x) + bf2f(b.x);
        ay += bf2f(a.y) + bf2f(b.y);
    }
    if (j < end) {
        ushort2 a = src[(size_t)lst[j] * Dh + c];
        ax += bf2f(a.x);
        ay += bf2f(a.y);
    }
    int cnt = end - beg;
    float inv = (cnt > 0) ? 1.f / (float)cnt : 0.f;
    float2 o = make_float2(ax * inv, ay * inv);
    *(float2*)&dst[(size_t)t * (2 * Dh) + 2 * c] = o;
}

// bf16 src -> relu -> bf16 dst (e2v producing h1/h2)
__global__ void seg_mean_b2b_relu(const ushort2* __restrict__ src, ushort2* __restrict__ dst,
                                  const int* __restrict__ off, const int* __restrict__ lst)
{
    int t  = blockIdx.x;
    int c  = threadIdx.x;
    int Dh = blockDim.x;
    int beg = off[t], end = off[t + 1];
    float ax = 0.f, ay = 0.f;
    int j = beg;
    for (; j + 1 < end; j += 2) {
        int i0 = lst[j], i1 = lst[j + 1];
        ushort2 a = src[(size_t)i0 * Dh + c];
        ushort2 b = src[(size_t)i1 * Dh + c];
        ax += bf2f(a.x) + bf2f(b.x);
        ay += bf2f(a.y) + bf2f(b.y);
    }
    if (j < end) {
        ushort2 a = src[(size_t)lst[j] * Dh + c];
        ax += bf2f(a.x);
        ay += bf2f(a.y);
    }
    int cnt = end - beg;
    float inv = (cnt > 0) ? 1.f / (float)cnt : 0.f;
    ushort2 o;
    o.x = f2bf(fmaxf(ax * inv, 0.f));
    o.y = f2bf(fmaxf(ay * inv, 0.f));
    dst[(size_t)t * Dh + c] = o;
}

// ======================= fp32 tiled GEMM + bias, bf16 out =======================
// C[R x Cc](bf16) = A[R x K](f32) @ W[K x Cc](f32) + bias.  64x64 tile, BK=16.
#define BM 64
#define BN 64
#define BK 16
__global__ __launch_bounds__(256) void gemm_bias_bf16out(const float* __restrict__ A,
                                                         const float* __restrict__ W,
                                                         const float* __restrict__ bias,
                                                         u16* __restrict__ C,
                                                         int R, int K, int Cc)
{
    __shared__ __align__(16) float As[BK][68];   // A^T tile: As[k][row]
    __shared__ __align__(16) float Bs[BK][72];   // Bs[k][col]

    int tid  = threadIdx.x;
    int row0 = blockIdx.y * BM;
    int col0 = blockIdx.x * BN;

    int tr = tid >> 4;        // 0..15
    int tc = tid & 15;        // 0..15

    float acc[4][4] = {};

    int ar = tid >> 2;        // 0..63
    int ac = tid & 3;         // 0..3
    int kr = tid >> 4;        // 0..15
    int cc = tid & 15;        // 0..15

    for (int k0 = 0; k0 < K; k0 += BK) {
        float4 av4 = make_float4(0.f, 0.f, 0.f, 0.f);
        int grow = row0 + ar;
        if (grow < R) av4 = *(const float4*)&A[(size_t)grow * K + k0 + 4 * ac];
        As[4 * ac + 0][ar] = av4.x;
        As[4 * ac + 1][ar] = av4.y;
        As[4 * ac + 2][ar] = av4.z;
        As[4 * ac + 3][ar] = av4.w;
        *(float4*)&Bs[kr][4 * cc] =
            *(const float4*)&W[(size_t)(k0 + kr) * Cc + col0 + 4 * cc];
        __syncthreads();

#pragma unroll
        for (int kk = 0; kk < BK; ++kk) {
            float4 a = *(const float4*)&As[kk][4 * tr];
            float4 b = *(const float4*)&Bs[kk][4 * tc];
            acc[0][0] += a.x * b.x; acc[0][1] += a.x * b.y; acc[0][2] += a.x * b.z; acc[0][3] += a.x * b.w;
            acc[1][0] += a.y * b.x; acc[1][1] += a.y * b.y; acc[1][2] += a.y * b.z; acc[1][3] += a.y * b.w;
            acc[2][0] += a.z * b.x; acc[2][1] += a.z * b.y; acc[2][2] += a.z * b.z; acc[2][3] += a.z * b.w;
            acc[3][0] += a.w * b.x; acc[3][1] += a.w * b.y; acc[3][2] += a.w * b.z; acc[3][3] += a.w * b.w;
        }
        __syncthreads();
    }

    int colb = col0 + 4 * tc;
    float4 bv = *(const float4*)&bias[colb];
#pragma unroll
    for (int i = 0; i < 4; ++i) {
        int grow = row0 + 4 * tr + i;
        if (grow < R) {
            ushort4 o;
            o.x = f2bf(acc[i][0] + bv.x);
            o.y = f2bf(acc[i][1] + bv.y);
            o.z = f2bf(acc[i][2] + bv.z);
            o.w = f2bf(acc[i][3] + bv.w);
            *(ushort4*)&C[(size_t)grow * Cc + colb] = o;
        }
    }
}

// ======================= link head =======================
// One wave per link: mean of K=2 member rows (bf16), dot fc_w (f32), sigmoid.
__global__ void link_head(const ushort2* __restrict__ h2, const int* __restrict__ link,
                          const float* __restrict__ fc_w, const float* __restrict__ fc_b,
                          float* __restrict__ out, int L)
{
    int gtid = blockIdx.x * blockDim.x + threadIdx.x;
    int wid  = gtid >> 6;
    int lane = threadIdx.x & 63;
    if (wid >= L) return;
    const int Dh = OUT_DIM / 2;   // 64 pairs
    int a = link[2 * wid + 0];
    int b = link[2 * wid + 1];
    ushort2 ra = h2[(size_t)a * Dh + lane];
    ushort2 rb = h2[(size_t)b * Dh + lane];
    float2 w = *(const float2*)&fc_w[2 * lane];
    float acc = 0.5f * ((bf2f(ra.x) + bf2f(rb.x)) * w.x + (bf2f(ra.y) + bf2f(rb.y)) * w.y);
#pragma unroll
    for (int off = 32; off; off >>= 1) acc += __shfl_xor(acc, off, 64);
    if (lane == 0) out[wid] = 1.f / (1.f + expf(-(acc + fc_b[0])));
}

// ======================= launch =======================

static inline size_t align_up(size_t x, size_t a) { return (x + a - 1) & ~(a - 1); }

extern "C" void kernel_launch(void* const* d_in, const int* in_sizes, int n_in,
                              void* d_out, int out_size, void* d_ws, size_t ws_size,
                              hipStream_t stream)
{
    const float* X   = (const float*)d_in[0];
    const float* W1  = (const float*)d_in[1];
    const float* b1  = (const float*)d_in[2];
    const float* W2  = (const float*)d_in[3];
    const float* b2  = (const float*)d_in[4];
    const float* fcw = (const float*)d_in[5];
    const float* fcb = (const float*)d_in[6];
    const int* v_idx = (const int*)d_in[7];
    const int* e_idx = (const int*)d_in[8];
    const int* link  = (const int*)d_in[9];
    float* out = (float*)d_out;

    const int NNZ = in_sizes[7];
    const int N   = in_sizes[0] / IN_DIM;
    const int L   = in_sizes[9] / 2;
    const int M   = MEDGES;

    char* p = (char*)d_ws;
    auto carve = [&](size_t bytes) -> void* {
        void* r = (void*)p;
        p += align_up(bytes, 256);
        return r;
    };
    u16*  Xb    = (u16*)carve((size_t)N * IN_DIM * 2);   // X in bf16; reused as h2b (N x 128)
    u16*  h1b   = (u16*)carve((size_t)N * H_DIM * 2);    // h1 in bf16
    float* Agg  = (float*)carve((size_t)M * H_DIM * 4);  // Xe / He (fp32, GEMM A)
    u16*  Yb    = (u16*)carve((size_t)M * H_DIM * 2);    // Y1b / Y2b
    int*  e_off = (int*)carve((size_t)(M + 1) * 4);
    int*  v_off = (int*)carve((size_t)(N + 1) * 4);
    int*  cnt_e = (int*)carve((size_t)M * 4);
    int*  cnt_v = (int*)carve((size_t)N * 4);
    int*  rank_e= (int*)carve((size_t)NNZ * 4);
    int*  rank_v= (int*)carve((size_t)NNZ * 4);
    int*  e_lst = (int*)carve((size_t)NNZ * 4);
    int*  v_lst = (int*)carve((size_t)NNZ * 4);
    int*  bsums = (int*)carve(4096);

    hipMemsetAsync(cnt_e, 0, (size_t)M * 4, stream);
    hipMemsetAsync(cnt_v, 0, (size_t)N * 4, stream);

    const int tb = 256;

    // X -> bf16 (runs while CSR build proceeds on other CUs)
    int n4 = N * IN_DIM / 4;
    cvt_f32_bf16<<<(n4 + tb - 1) / tb, tb, 0, stream>>>((const float4*)X, (ushort4*)Xb, n4);

    hist_rank_kernel<<<(NNZ + tb - 1) / tb, tb, 0, stream>>>(e_idx, v_idx, cnt_e, cnt_v,
                                                             rank_e, rank_v, NNZ);

    int nbE = (M + SCAN_B - 1) / SCAN_B;
    scan_block_kernel<<<nbE, SCAN_B, 0, stream>>>(cnt_e, e_off, bsums, M);
    scan_top_kernel<<<1, 64, 0, stream>>>(bsums, nbE);
    scan_add_kernel<<<nbE, SCAN_B, 0, stream>>>(e_off, bsums, M);

    int nbV = (N + SCAN_B - 1) / SCAN_B;
    scan_block_kernel<<<nbV, SCAN_B, 0, stream>>>(cnt_v, v_off, bsums, N);
    scan_top_kernel<<<1, 64, 0, stream>>>(bsums, nbV);
    scan_add_kernel<<<nbV, SCAN_B, 0, stream>>>(v_off, bsums, N);

    set_tail_kernel<<<1, 64, 0, stream>>>(e_off, v_off, NNZ, M, N);

    scatter_kernel<<<(NNZ + tb - 1) / tb, tb, 0, stream>>>(e_idx, v_idx, e_off, v_off,
                                                           rank_e, rank_v, e_lst, v_lst, NNZ);

    // ---- conv1 (GEMM commuted to edge level; all gathered tensors bf16) ----
    // Xe = mean_v2e(Xb)                [M x 256] f32
    seg_mean_b2f<<<M, IN_DIM / 2, 0, stream>>>((const ushort2*)Xb, Agg, e_off, e_lst);
    // Y1b = bf16(Xe @ W1 + b1)         [M x 256]
    gemm_bias_bf16out<<<dim3(H_DIM / BN, (M + BM - 1) / BM), 256, 0, stream>>>(Agg, W1, b1, Yb, M, IN_DIM, H_DIM);
    // h1b = bf16(relu(mean_e2v(Y1b)))  [N x 256]
    seg_mean_b2b_relu<<<N, H_DIM / 2, 0, stream>>>((const ushort2*)Yb, (ushort2*)h1b, v_off, v_lst);

    // ---- conv2 ----
    // He = mean_v2e(h1b)               [M x 256] f32 (reuses Agg)
    seg_mean_b2f<<<M, H_DIM / 2, 0, stream>>>((const ushort2*)h1b, Agg, e_off, e_lst);
    // Y2b = bf16(He @ W2 + b2)         [M x 128] (reuses Yb)
    gemm_bias_bf16out<<<dim3(OUT_DIM / BN, (M + BM - 1) / BM), 256, 0, stream>>>(Agg, W2, b2, Yb, M, H_DIM, OUT_DIM);
    // h2b = bf16(relu(mean_e2v(Y2b)))  [N x 128] (reuses Xb)
    seg_mean_b2b_relu<<<N, OUT_DIM / 2, 0, stream>>>((const ushort2*)Yb, (ushort2*)Xb, v_off, v_lst);

    // ---- link head ----
    link_head<<<((size_t)L * 64 + 255) / 256, 256, 0, stream>>>((const ushort2*)Xb, link, fcw, fcb, out, L);
}

// Round 4
// 630.987 us; speedup vs baseline: 1.5878x; 1.0737x over previous
//
#include <hip/hip_runtime.h>
#include <cstdint>
#include <cstddef>

#define IN_DIM  256
#define H_DIM   256
#define OUT_DIM 128
#define MEDGES  20000

typedef unsigned short u16;
typedef unsigned int   u32;
typedef short bf16x8 __attribute__((ext_vector_type(8)));
typedef float f32x4  __attribute__((ext_vector_type(4)));

__device__ __forceinline__ float bf2f(u16 u) {
    u32 x = ((u32)u) << 16;
    float f;
    __builtin_memcpy(&f, &x, 4);
    return f;
}
// round-to-nearest-even float -> bf16 (finite inputs)
__device__ __forceinline__ u16 f2bf(float f) {
    u32 x;
    __builtin_memcpy(&x, &f, 4);
    u32 r = x + 0x7fffu + ((x >> 16) & 1u);
    return (u16)(r >> 16);
}

// ======================= convert fp32 -> bf16 =======================
__global__ void cvt_f32_bf16(const float4* __restrict__ src, ushort4* __restrict__ dst, int n4)
{
    int i = blockIdx.x * blockDim.x + threadIdx.x;
    if (i < n4) {
        float4 v = src[i];
        ushort4 o;
        o.x = f2bf(v.x); o.y = f2bf(v.y); o.z = f2bf(v.z); o.w = f2bf(v.w);
        dst[i] = o;
    }
}

// ======================= CSR build =======================

__global__ void hist_rank_kernel(const int* __restrict__ e_idx, const int* __restrict__ v_idx,
                                 int* __restrict__ cnt_e, int* __restrict__ cnt_v,
                                 int* __restrict__ rank_e, int* __restrict__ rank_v, int nnz)
{
    int i = blockIdx.x * blockDim.x + threadIdx.x;
    if (i < nnz) {
        rank_e[i] = atomicAdd(&cnt_e[e_idx[i]], 1);
        rank_v[i] = atomicAdd(&cnt_v[v_idx[i]], 1);
    }
}

#define SCAN_B 1024
__global__ void scan_block_kernel(const int* __restrict__ in, int* __restrict__ out,
                                  int* __restrict__ bsums, int n)
{
    __shared__ int s[SCAN_B];
    int gid = blockIdx.x * SCAN_B + threadIdx.x;
    int x = (gid < n) ? in[gid] : 0;
    s[threadIdx.x] = x;
    __syncthreads();
    for (int off = 1; off < SCAN_B; off <<= 1) {
        int v = (threadIdx.x >= off) ? s[threadIdx.x - off] : 0;
        __syncthreads();
        s[threadIdx.x] += v;
        __syncthreads();
    }
    if (gid < n) out[gid] = s[threadIdx.x] - x;   // exclusive
    if (threadIdx.x == SCAN_B - 1) bsums[blockIdx.x] = s[SCAN_B - 1];
}

__global__ void scan_top_kernel(int* bsums, int nb)
{
    if (threadIdx.x == 0 && blockIdx.x == 0) {
        int run = 0;
        for (int i = 0; i < nb; ++i) { int v = bsums[i]; bsums[i] = run; run += v; }
    }
}

__global__ void scan_add_kernel(int* __restrict__ out, const int* __restrict__ bsums, int n)
{
    int gid = blockIdx.x * SCAN_B + threadIdx.x;
    if (gid < n) out[gid] += bsums[blockIdx.x];
}

__global__ void set_tail_kernel(int* e_off, int* v_off, int nnz, int m, int n)
{
    if (threadIdx.x == 0 && blockIdx.x == 0) { e_off[m] = nnz; v_off[n] = nnz; }
}

__global__ void scatter_kernel(const int* __restrict__ e_idx, const int* __restrict__ v_idx,
                               const int* __restrict__ e_off, const int* __restrict__ v_off,
                               const int* __restrict__ rank_e, const int* __restrict__ rank_v,
                               int* __restrict__ e_list, int* __restrict__ v_list, int nnz)
{
    int i = blockIdx.x * blockDim.x + threadIdx.x;
    if (i < nnz) {
        int e = e_idx[i], v = v_idx[i];
        e_list[e_off[e] + rank_e[i]] = v;
        v_list[v_off[v] + rank_v[i]] = e;
    }
}

// ======================= segment mean (gather, bf16 src -> bf16 dst) =======================
// One block per segment; blockDim.x = D/2; each thread owns one bf16x2 column pair.
__global__ void seg_mean_b2b(const ushort2* __restrict__ src, ushort2* __restrict__ dst,
                             const int* __restrict__ off, const int* __restrict__ lst,
                             int do_relu)
{
    int t  = blockIdx.x;
    int c  = threadIdx.x;
    int Dh = blockDim.x;
    int beg = off[t], end = off[t + 1];
    float ax = 0.f, ay = 0.f;
    int j = beg;
    for (; j + 1 < end; j += 2) {
        int i0 = lst[j], i1 = lst[j + 1];
        ushort2 a = src[(size_t)i0 * Dh + c];
        ushort2 b = src[(size_t)i1 * Dh + c];
        ax += bf2f(a.x) + bf2f(b.x);
        ay += bf2f(a.y) + bf2f(b.y);
    }
    if (j < end) {
        ushort2 a = src[(size_t)lst[j] * Dh + c];
        ax += bf2f(a.x);
        ay += bf2f(a.y);
    }
    int cnt = end - beg;
    float inv = (cnt > 0) ? 1.f / (float)cnt : 0.f;
    ax *= inv; ay *= inv;
    if (do_relu) { ax = fmaxf(ax, 0.f); ay = fmaxf(ay, 0.f); }
    ushort2 o;
    o.x = f2bf(ax);
    o.y = f2bf(ay);
    dst[(size_t)t * Dh + c] = o;
}

// ======================= MFMA bf16 GEMM + bias, bf16 out =======================
// C[R x Cc](bf16) = A[R x K](bf16) @ W[K x Cc](bf16) + bias(f32).
// 64x64 tile, BK=32, 256 threads = 4 waves; wave w computes rows [16w,16w+16).
// mfma_f32_16x16x32_bf16: A-frag A[m=lane&15][k=quad*8+j]; B-frag B[k=quad*8+j][n=lane&15];
// D: col=lane&15, row=quad*4+reg.
#define GSTRIDE 40   // LDS row stride in elements (80 B: 16B-aligned rows, <=2-way banks)
__global__ __launch_bounds__(256) void gemm_mfma_bf16(const u16* __restrict__ A,
                                                      const u16* __restrict__ W,
                                                      const float* __restrict__ bias,
                                                      u16* __restrict__ C,
                                                      int R, int K, int Cc)
{
    __shared__ __align__(16) u16 As[64 * GSTRIDE];   // [row][k] 64x32
    __shared__ __align__(16) u16 Bs[64 * GSTRIDE];   // [n][k]   64x32 (transposed)

    int tid  = threadIdx.x;
    int wave = tid >> 6;
    int lane = tid & 63;
    int quad = lane >> 4;
    int l16  = lane & 15;

    int row0 = blockIdx.y * 64;
    int col0 = blockIdx.x * 64;

    f32x4 acc[4] = {};   // 4 n-tiles of 16 cols

    int ar   = tid >> 2;   // 0..63 A row
    int aseg = tid & 3;    // k-offset 8*aseg
    int bk   = tid >> 3;   // 0..31 W k-row
    int bn   = tid & 7;    // n-offset 8*bn

    for (int k0 = 0; k0 < K; k0 += 32) {
        // stage A
        bf16x8 av = {};
        int gr = row0 + ar;
        if (gr < R) av = *(const bf16x8*)&A[(size_t)gr * K + k0 + 8 * aseg];
        *(bf16x8*)&As[ar * GSTRIDE + 8 * aseg] = av;
        // stage W transposed: Bs[n][k]
        bf16x8 wv = *(const bf16x8*)&W[(size_t)(k0 + bk) * Cc + col0 + 8 * bn];
#pragma unroll
        for (int j = 0; j < 8; ++j)
            Bs[(8 * bn + j) * GSTRIDE + bk] = ((const u16*)&wv)[j];
        __syncthreads();

        bf16x8 af = *(const bf16x8*)&As[(16 * wave + l16) * GSTRIDE + 8 * quad];
#pragma unroll
        for (int nt = 0; nt < 4; ++nt) {
            bf16x8 bfv = *(const bf16x8*)&Bs[(16 * nt + l16) * GSTRIDE + 8 * quad];
            acc[nt] = __builtin_amdgcn_mfma_f32_16x16x32_bf16(af, bfv, acc[nt], 0, 0, 0);
        }
        __syncthreads();
    }

    // epilogue
#pragma unroll
    for (int nt = 0; nt < 4; ++nt) {
        int col = col0 + 16 * nt + l16;
        float bv = bias[col];
#pragma unroll
        for (int r = 0; r < 4; ++r) {
            int grow = row0 + 16 * wave + 4 * quad + r;
            if (grow < R) C[(size_t)grow * Cc + col] = f2bf(acc[nt][r] + bv);
        }
    }
}

// ======================= link head =======================
__global__ void link_head(const ushort2* __restrict__ h2, const int* __restrict__ link,
                          const float* __restrict__ fc_w, const float* __restrict__ fc_b,
                          float* __restrict__ out, int L)
{
    int gtid = blockIdx.x * blockDim.x + threadIdx.x;
    int wid  = gtid >> 6;
    int lane = threadIdx.x & 63;
    if (wid >= L) return;
    const int Dh = OUT_DIM / 2;   // 64 pairs
    int a = link[2 * wid + 0];
    int b = link[2 * wid + 1];
    ushort2 ra = h2[(size_t)a * Dh + lane];
    ushort2 rb = h2[(size_t)b * Dh + lane];
    float2 w = *(const float2*)&fc_w[2 * lane];
    float acc = 0.5f * ((bf2f(ra.x) + bf2f(rb.x)) * w.x + (bf2f(ra.y) + bf2f(rb.y)) * w.y);
#pragma unroll
    for (int off = 32; off; off >>= 1) acc += __shfl_xor(acc, off, 64);
    if (lane == 0) out[wid] = 1.f / (1.f + expf(-(acc + fc_b[0])));
}

// ======================= launch =======================

static inline size_t align_up(size_t x, size_t a) { return (x + a - 1) & ~(a - 1); }

extern "C" void kernel_launch(void* const* d_in, const int* in_sizes, int n_in,
                              void* d_out, int out_size, void* d_ws, size_t ws_size,
                              hipStream_t stream)
{
    const float* X   = (const float*)d_in[0];
    const float* W1  = (const float*)d_in[1];
    const float* b1  = (const float*)d_in[2];
    const float* W2  = (const float*)d_in[3];
    const float* b2  = (const float*)d_in[4];
    const float* fcw = (const float*)d_in[5];
    const float* fcb = (const float*)d_in[6];
    const int* v_idx = (const int*)d_in[7];
    const int* e_idx = (const int*)d_in[8];
    const int* link  = (const int*)d_in[9];
    float* out = (float*)d_out;

    const int NNZ = in_sizes[7];
    const int N   = in_sizes[0] / IN_DIM;
    const int L   = in_sizes[9] / 2;
    const int M   = MEDGES;

    char* p = (char*)d_ws;
    auto carve = [&](size_t bytes) -> void* {
        void* r = (void*)p;
        p += align_up(bytes, 256);
        return r;
    };
    u16*  Xb    = (u16*)carve((size_t)N * IN_DIM * 2);   // X bf16; reused as h2b (N x 128)
    u16*  h1b   = (u16*)carve((size_t)N * H_DIM * 2);    // h1 bf16
    u16*  Aggb  = (u16*)carve((size_t)M * H_DIM * 2);    // Xe/He bf16 (GEMM A)
    u16*  Yb    = (u16*)carve((size_t)M * H_DIM * 2);    // Y1b / Y2b
    u16*  W1b   = (u16*)carve((size_t)IN_DIM * H_DIM * 2);
    u16*  W2b   = (u16*)carve((size_t)H_DIM * OUT_DIM * 2);
    int*  e_off = (int*)carve((size_t)(M + 1) * 4);
    int*  v_off = (int*)carve((size_t)(N + 1) * 4);
    int*  cnt_e = (int*)carve((size_t)M * 4);
    int*  cnt_v = (int*)carve((size_t)N * 4);
    int*  rank_e= (int*)carve((size_t)NNZ * 4);
    int*  rank_v= (int*)carve((size_t)NNZ * 4);
    int*  e_lst = (int*)carve((size_t)NNZ * 4);
    int*  v_lst = (int*)carve((size_t)NNZ * 4);
    int*  bsums = (int*)carve(4096);

    (void)hipMemsetAsync(cnt_e, 0, (size_t)M * 4, stream);
    (void)hipMemsetAsync(cnt_v, 0, (size_t)N * 4, stream);

    const int tb = 256;

    // converts (overlap with CSR build on other CUs)
    int n4 = N * IN_DIM / 4;
    cvt_f32_bf16<<<(n4 + tb - 1) / tb, tb, 0, stream>>>((const float4*)X, (ushort4*)Xb, n4);
    int w14 = IN_DIM * H_DIM / 4;
    cvt_f32_bf16<<<(w14 + tb - 1) / tb, tb, 0, stream>>>((const float4*)W1, (ushort4*)W1b, w14);
    int w24 = H_DIM * OUT_DIM / 4;
    cvt_f32_bf16<<<(w24 + tb - 1) / tb, tb, 0, stream>>>((const float4*)W2, (ushort4*)W2b, w24);

    hist_rank_kernel<<<(NNZ + tb - 1) / tb, tb, 0, stream>>>(e_idx, v_idx, cnt_e, cnt_v,
                                                             rank_e, rank_v, NNZ);

    int nbE = (M + SCAN_B - 1) / SCAN_B;
    scan_block_kernel<<<nbE, SCAN_B, 0, stream>>>(cnt_e, e_off, bsums, M);
    scan_top_kernel<<<1, 64, 0, stream>>>(bsums, nbE);
    scan_add_kernel<<<nbE, SCAN_B, 0, stream>>>(e_off, bsums, M);

    int nbV = (N + SCAN_B - 1) / SCAN_B;
    scan_block_kernel<<<nbV, SCAN_B, 0, stream>>>(cnt_v, v_off, bsums, N);
    scan_top_kernel<<<1, 64, 0, stream>>>(bsums, nbV);
    scan_add_kernel<<<nbV, SCAN_B, 0, stream>>>(v_off, bsums, N);

    set_tail_kernel<<<1, 64, 0, stream>>>(e_off, v_off, NNZ, M, N);

    scatter_kernel<<<(NNZ + tb - 1) / tb, tb, 0, stream>>>(e_idx, v_idx, e_off, v_off,
                                                           rank_e, rank_v, e_lst, v_lst, NNZ);

    // ---- conv1 ----
    // Aggb = bf16(mean_v2e(Xb))        [M x 256]
    seg_mean_b2b<<<M, IN_DIM / 2, 0, stream>>>((const ushort2*)Xb, (ushort2*)Aggb, e_off, e_lst, 0);
    // Y1b = bf16(Aggb @ W1b + b1)      [M x 256]  (MFMA)
    gemm_mfma_bf16<<<dim3(H_DIM / 64, (M + 63) / 64), 256, 0, stream>>>(Aggb, W1b, b1, Yb, M, IN_DIM, H_DIM);
    // h1b = bf16(relu(mean_e2v(Y1b)))  [N x 256]
    seg_mean_b2b<<<N, H_DIM / 2, 0, stream>>>((const ushort2*)Yb, (ushort2*)h1b, v_off, v_lst, 1);

    // ---- conv2 ----
    // Aggb = bf16(mean_v2e(h1b))       [M x 256]
    seg_mean_b2b<<<M, H_DIM / 2, 0, stream>>>((const ushort2*)h1b, (ushort2*)Aggb, e_off, e_lst, 0);
    // Y2b = bf16(Aggb @ W2b + b2)      [M x 128]  (MFMA)
    gemm_mfma_bf16<<<dim3(OUT_DIM / 64, (M + 63) / 64), 256, 0, stream>>>(Aggb, W2b, b2, Yb, M, H_DIM, OUT_DIM);
    // h2b = bf16(relu(mean_e2v(Y2b)))  [N x 128]  (reuses Xb)
    seg_mean_b2b<<<N, OUT_DIM / 2, 0, stream>>>((const ushort2*)Yb, (ushort2*)Xb, v_off, v_lst, 1);

    // ---- link head ----
    link_head<<<((size_t)L * 64 + 255) / 256, 256, 0, stream>>>((const ushort2*)Xb, link, fcw, fcb, out, L);
}